// Round 1
// baseline (391.679 us; speedup 1.0000x reference)
//
#include <hip/hip_runtime.h>
#include <cmath>

#define BLOCK 1024
#define NW (BLOCK / 64)

// inclusive scan across a 64-lane wave (lane order = index order)
__device__ __forceinline__ float wincl(float v, int lane) {
#pragma unroll
    for (int o = 1; o < 64; o <<= 1) {
        float x = __shfl_up(v, o, 64);
        if (lane >= o) v += x;
    }
    return v;
}

// Walk buckets in DESCENDING value order; find first bucket where running
// inclusive mass (starting at base0) exceeds limit. Executed by one full wave.
// Returns critical bucket index and A = mass strictly above it (uniform in all lanes).
__device__ __forceinline__ void find_crit_desc(const float* h, int n, int seg,
                                               float base0, float limit, int lane,
                                               int* out_b, float* out_A) {
    float segsum = 0.f;
    int start = n - 1 - lane * seg;
    for (int k = 0; k < seg; k++) segsum += h[start - k];
    float incl = wincl(segsum, lane);
    unsigned long long mk = __ballot(base0 + incl > limit);
    if (mk == 0ULL) { *out_b = 0; *out_A = base0; return; }  // keep everything
    int fl = __ffsll(mk) - 1;
    float base = base0 + __shfl(incl, fl, 64) - __shfl(segsum, fl, 64);
    int sstart = n - 1 - fl * seg;
    float v = (lane < seg) ? h[sstart - lane] : 0.f;
    float incl2 = wincl(v, lane);
    unsigned long long mk2 = __ballot((lane < seg) && (base + incl2 > limit));
    int k2 = mk2 ? (__ffsll(mk2) - 1) : (seg - 1);
    *out_b = sstart - k2;
    *out_A = base + __shfl(incl2, k2, 64) - __shfl(v, k2, 64);
}

__global__ __launch_bounds__(BLOCK) void NucleusSampling_79336635892529_kernel(
    const float* __restrict__ logits, const float* __restrict__ uvec,
    const int* __restrict__ temp, int* __restrict__ out, int Vv) {
    const int b = blockIdx.x;
    const float* __restrict__ row = logits + (size_t)b * (size_t)Vv;
    const int t = threadIdx.x;
    const int lane = t & 63;
    const int wave = t >> 6;

    __shared__ float hist[4096];
    __shared__ float sweep[NW];
    __shared__ float csum[256];
    __shared__ float fb[2];
    __shared__ int ib[2];
    __shared__ unsigned int ub[1];

    const float inv_t = 1.0f / (float)temp[0];
    const int V4 = Vv & ~3;

    // ---------------- P1: max of scaled logits ----------------
    float m = -INFINITY;
    for (int i = t * 4; i < V4; i += BLOCK * 4) {
        float4 v = *(const float4*)(row + i);
        m = fmaxf(m, fmaxf(fmaxf(v.x * inv_t, v.y * inv_t),
                           fmaxf(v.z * inv_t, v.w * inv_t)));
    }
    for (int i = V4 + t; i < Vv; i += BLOCK) m = fmaxf(m, row[i] * inv_t);
#pragma unroll
    for (int o = 32; o >= 1; o >>= 1) m = fmaxf(m, __shfl_xor(m, o, 64));
    if (lane == 0) sweep[wave] = m;
    __syncthreads();
    float M = sweep[0];
    for (int w = 1; w < NW; w++) M = fmaxf(M, sweep[w]);
    for (int i = t; i < 2048; i += BLOCK) hist[i] = 0.f;   // zero L1 hist
    __syncthreads();

    // ---------------- P2: Z + level-1 histogram (2048 buckets) ----------------
    float zp = 0.f;
    for (int i = t * 4; i < V4; i += BLOCK * 4) {
        float4 v = *(const float4*)(row + i);
        float e0 = __expf(v.x * inv_t - M);
        float e1 = __expf(v.y * inv_t - M);
        float e2 = __expf(v.z * inv_t - M);
        float e3 = __expf(v.w * inv_t - M);
        zp += (e0 + e1) + (e2 + e3);
        atomicAdd(&hist[__float_as_uint(e0) >> 19], e0);
        atomicAdd(&hist[__float_as_uint(e1) >> 19], e1);
        atomicAdd(&hist[__float_as_uint(e2) >> 19], e2);
        atomicAdd(&hist[__float_as_uint(e3) >> 19], e3);
    }
    for (int i = V4 + t; i < Vv; i += BLOCK) {
        float e = __expf(row[i] * inv_t - M);
        zp += e;
        atomicAdd(&hist[__float_as_uint(e) >> 19], e);
    }
#pragma unroll
    for (int o = 32; o >= 1; o >>= 1) zp += __shfl_xor(zp, o, 64);
    __syncthreads();                 // hist complete; sweep reads from P1 done
    if (lane == 0) sweep[wave] = zp;
    __syncthreads();
    float Z = 0.f;
    for (int w = 0; w < NW; w++) Z += sweep[w];
    const float limit = 0.9f * Z;

    // ---------------- L1 walk: critical bucket ----------------
    if (wave == 0) {
        int b1w; float Aw;
        find_crit_desc(hist, 2048, 32, 0.f, limit, lane, &b1w, &Aw);
        if (lane == 0) { ib[0] = b1w; fb[0] = Aw; }
    }
    __syncthreads();
    const int b1 = ib[0];
    const float A = fb[0];
    for (int i = t; i < 4096; i += BLOCK) hist[i] = 0.f;   // zero L2 hist
    __syncthreads();

    // ---------------- P3: level-2 histogram inside critical bucket ----------------
    for (int i = t * 4; i < V4; i += BLOCK * 4) {
        float4 v = *(const float4*)(row + i);
        float e0 = __expf(v.x * inv_t - M);
        float e1 = __expf(v.y * inv_t - M);
        float e2 = __expf(v.z * inv_t - M);
        float e3 = __expf(v.w * inv_t - M);
        unsigned u0 = __float_as_uint(e0), u1 = __float_as_uint(e1);
        unsigned u2 = __float_as_uint(e2), u3 = __float_as_uint(e3);
        if ((int)(u0 >> 19) == b1) atomicAdd(&hist[(u0 >> 7) & 0xFFF], e0);
        if ((int)(u1 >> 19) == b1) atomicAdd(&hist[(u1 >> 7) & 0xFFF], e1);
        if ((int)(u2 >> 19) == b1) atomicAdd(&hist[(u2 >> 7) & 0xFFF], e2);
        if ((int)(u3 >> 19) == b1) atomicAdd(&hist[(u3 >> 7) & 0xFFF], e3);
    }
    for (int i = V4 + t; i < Vv; i += BLOCK) {
        float e = __expf(row[i] * inv_t - M);
        unsigned uu = __float_as_uint(e);
        if ((int)(uu >> 19) == b1) atomicAdd(&hist[(uu >> 7) & 0xFFF], e);
    }
    __syncthreads();
    if (wave == 0) {
        int b2w; float A2w;
        find_crit_desc(hist, 4096, 64, A, limit, lane, &b2w, &A2w);
        if (lane == 0) ub[0] = (((unsigned)b1 << 12) | (unsigned)b2w) << 7;
    }
    __syncthreads();
    const unsigned T = ub[0];   // kept <=> float bits of e >= T

    // ---------------- P4: chunk sums of kept mass, then locate token ----------------
    const int nch = (Vv + 511) >> 9;    // 512-element chunks (250 for V=128000)
    for (int c = wave; c < nch; c += NW) {
        float s = 0.f;
        int base = c << 9;
#pragma unroll
        for (int r = 0; r < 2; r++) {
            int i = base + r * 256 + lane * 4;
            if (i + 3 < Vv) {
                float4 v = *(const float4*)(row + i);
                float e0 = __expf(v.x * inv_t - M);
                float e1 = __expf(v.y * inv_t - M);
                float e2 = __expf(v.z * inv_t - M);
                float e3 = __expf(v.w * inv_t - M);
                if (__float_as_uint(e0) >= T) s += e0;
                if (__float_as_uint(e1) >= T) s += e1;
                if (__float_as_uint(e2) >= T) s += e2;
                if (__float_as_uint(e3) >= T) s += e3;
            } else {
                for (int k = 0; k < 4; k++) {
                    if (i + k < Vv) {
                        float e = __expf(row[i + k] * inv_t - M);
                        if (__float_as_uint(e) >= T) s += e;
                    }
                }
            }
        }
#pragma unroll
        for (int o = 32; o >= 1; o >>= 1) s += __shfl_xor(s, o, 64);
        if (lane == 0) csum[c] = s;
    }
    if (t < 256 && t >= nch) csum[t] = 0.f;
    __syncthreads();

    if (wave == 0) {
        // ascending scan over chunk sums (seg = 4, covers 256 slots)
        float segsum = 0.f;
#pragma unroll
        for (int k = 0; k < 4; k++) segsum += csum[lane * 4 + k];
        float incl = wincl(segsum, lane);
        float total = __shfl(incl, 63, 64);            // Z_kept
        const float U = uvec[b] * total;
        unsigned long long mk = __ballot(incl >= U);
        int token;
        if (mk == 0ULL) {
            token = Vv;                                // u beyond total mass
        } else {
            int fl = __ffsll(mk) - 1;
            float base = __shfl(incl, fl, 64) - __shfl(segsum, fl, 64);
            float v = (lane < 4) ? csum[fl * 4 + lane] : 0.f;
            float incl2 = wincl(v, lane);
            unsigned long long mk2 = __ballot((lane < 4) && (base + incl2 >= U));
            int k2 = mk2 ? (__ffsll(mk2) - 1) : 3;
            int cx = fl * 4 + k2;                      // crossing chunk
            float B = base + __shfl(incl2, k2, 64) - __shfl(v, k2, 64);
            // in-order scan of the single crossing chunk
            int cnt = 0;
            int cb = cx << 9;
#pragma unroll
            for (int r = 0; r < 8; r++) {
                int i = cb + r * 64 + lane;
                float e = 0.f;
                if (i < Vv) {
                    float ev = __expf(row[i] * inv_t - M);
                    if (__float_as_uint(ev) >= T) e = ev;
                }
                float is = wincl(e, lane);
                unsigned long long mm = __ballot((i < Vv) && (B + is < U));
                cnt += __popcll(mm);
                B += __shfl(is, 63, 64);
            }
            token = cb + cnt;
        }
        if (lane == 0) out[b] = (token < Vv - 1) ? token : (Vv - 1);
    }
}

extern "C" void kernel_launch(void* const* d_in, const int* in_sizes, int n_in,
                              void* d_out, int out_size, void* d_ws, size_t ws_size,
                              hipStream_t stream) {
    const float* logits = (const float*)d_in[0];
    const float* u = (const float*)d_in[1];
    const int* temp = (const int*)d_in[2];
    int* out = (int*)d_out;
    int B = in_sizes[1];
    int V = in_sizes[0] / B;
    NucleusSampling_79336635892529_kernel<<<B, BLOCK, 0, stream>>>(logits, u, temp, out, V);
}

// Round 2
// 387.666 us; speedup vs baseline: 1.0104x; 1.0104x over previous
//
#include <hip/hip_runtime.h>
#include <cmath>

#define BLOCK 1024
#define NW (BLOCK / 64)

// inclusive scan across a 64-lane wave (lane order = index order)
__device__ __forceinline__ float wincl(float v, int lane) {
#pragma unroll
    for (int o = 1; o < 64; o <<= 1) {
        float x = __shfl_up(v, o, 64);
        if (lane >= o) v += x;
    }
    return v;
}

// Walk buckets in DESCENDING value order; find first bucket where running
// inclusive mass (starting at base0) exceeds limit. One full wave executes.
__device__ __forceinline__ void find_crit_desc(const float* h, int n, int seg,
                                               float base0, float limit, int lane,
                                               int* out_b, float* out_A) {
    float segsum = 0.f;
    int start = n - 1 - lane * seg;
    for (int k = 0; k < seg; k++) segsum += h[start - k];
    float incl = wincl(segsum, lane);
    unsigned long long mk = __ballot(base0 + incl > limit);
    if (mk == 0ULL) { *out_b = 0; *out_A = base0; return; }
    int fl = __ffsll(mk) - 1;
    float base = base0 + __shfl(incl, fl, 64) - __shfl(segsum, fl, 64);
    int sstart = n - 1 - fl * seg;
    float v = (lane < seg) ? h[sstart - lane] : 0.f;
    float incl2 = wincl(v, lane);
    unsigned long long mk2 = __ballot((lane < seg) && (base + incl2 > limit));
    int k2 = mk2 ? (__ffsll(mk2) - 1) : (seg - 1);
    *out_b = sstart - k2;
    *out_A = base + __shfl(incl2, k2, 64) - __shfl(v, k2, 64);
}

#define LD4(j) (*(const float4*)(row + (j)))
#define MAX4(v) m = fmaxf(m, fmaxf(fmaxf((v).x, (v).y), fmaxf((v).z, (v).w)))

__global__ __launch_bounds__(BLOCK) void NucleusSampling_79336635892529_kernel(
    const float* __restrict__ logits, const float* __restrict__ uvec,
    const int* __restrict__ temp, int* __restrict__ out, int Vv) {
    const int b = blockIdx.x;
    const float* __restrict__ row = logits + (size_t)b * (size_t)Vv;
    const int t = threadIdx.x;
    const int lane = t & 63;
    const int wave = t >> 6;

    __shared__ float hist[4096];
    __shared__ float sweep[NW];
    __shared__ float csum[128];       // 1024-elem chunks; V<=131072 assumed
    __shared__ float fb[1];
    __shared__ int ib[1];
    __shared__ unsigned int ub[1];

    const float inv_t = 1.0f / (float)temp[0];
    const int V4 = Vv & ~3;
    const int S = BLOCK * 4;          // elements per batched load round

    // ---------------- P1: max of raw logits (4 loads in flight) ----------------
    float m = -INFINITY;
    {
        int i = t * 4;
        for (; i + 3 * S + 3 < V4; i += 4 * S) {
            float4 a = LD4(i), b4 = LD4(i + S), c = LD4(i + 2 * S), d = LD4(i + 3 * S);
            MAX4(a); MAX4(b4); MAX4(c); MAX4(d);
        }
        for (; i < V4; i += S) { float4 a = LD4(i); MAX4(a); }
        for (int j = V4 + t; j < Vv; j += BLOCK) m = fmaxf(m, row[j]);
    }
#pragma unroll
    for (int o = 32; o >= 1; o >>= 1) m = fmaxf(m, __shfl_xor(m, o, 64));
    if (lane == 0) sweep[wave] = m;
    __syncthreads();
    float M = sweep[0];
    for (int w = 1; w < NW; w++) M = fmaxf(M, sweep[w]);
    M *= inv_t;                        // temperature > 0
    for (int i = t; i < 2048; i += BLOCK) hist[i] = 0.f;
    __syncthreads();

    // ---------------- P2: Z + level-1 histogram (2048 buckets) ----------------
    float zp = 0.f;
#define ACC1(ss) { float e = __expf((ss) * inv_t - M); zp += e; \
                   atomicAdd(&hist[__float_as_uint(e) >> 19], e); }
    {
        int i = t * 4;
        for (; i + 3 * S + 3 < V4; i += 4 * S) {
            float4 a = LD4(i), b4 = LD4(i + S), c = LD4(i + 2 * S), d = LD4(i + 3 * S);
            ACC1(a.x); ACC1(a.y); ACC1(a.z); ACC1(a.w);
            ACC1(b4.x); ACC1(b4.y); ACC1(b4.z); ACC1(b4.w);
            ACC1(c.x); ACC1(c.y); ACC1(c.z); ACC1(c.w);
            ACC1(d.x); ACC1(d.y); ACC1(d.z); ACC1(d.w);
        }
        for (; i < V4; i += S) {
            float4 a = LD4(i);
            ACC1(a.x); ACC1(a.y); ACC1(a.z); ACC1(a.w);
        }
        for (int j = V4 + t; j < Vv; j += BLOCK) ACC1(row[j]);
    }
#pragma unroll
    for (int o = 32; o >= 1; o >>= 1) zp += __shfl_xor(zp, o, 64);
    if (lane == 0) sweep[wave] = zp;
    __syncthreads();
    float Z = 0.f;
    for (int w = 0; w < NW; w++) Z += sweep[w];
    const float limit = 0.9f * Z;

    // ---------------- L1 walk: critical bucket ----------------
    if (wave == 0) {
        int b1w; float Aw;
        find_crit_desc(hist, 2048, 32, 0.f, limit, lane, &b1w, &Aw);
        if (lane == 0) { ib[0] = b1w; fb[0] = Aw; }
    }
    __syncthreads();
    const int b1 = ib[0];
    const float A = fb[0];
    for (int i = t; i < 4096; i += BLOCK) hist[i] = 0.f;
    __syncthreads();

    // ---------------- P3: level-2 histogram inside critical bucket ----------------
#define REF1(ss) { float e = __expf((ss) * inv_t - M); unsigned uu = __float_as_uint(e); \
                   if ((int)(uu >> 19) == b1) atomicAdd(&hist[(uu >> 7) & 0xFFF], e); }
    {
        int i = t * 4;
        for (; i + 3 * S + 3 < V4; i += 4 * S) {
            float4 a = LD4(i), b4 = LD4(i + S), c = LD4(i + 2 * S), d = LD4(i + 3 * S);
            REF1(a.x); REF1(a.y); REF1(a.z); REF1(a.w);
            REF1(b4.x); REF1(b4.y); REF1(b4.z); REF1(b4.w);
            REF1(c.x); REF1(c.y); REF1(c.z); REF1(c.w);
            REF1(d.x); REF1(d.y); REF1(d.z); REF1(d.w);
        }
        for (; i < V4; i += S) {
            float4 a = LD4(i);
            REF1(a.x); REF1(a.y); REF1(a.z); REF1(a.w);
        }
        for (int j = V4 + t; j < Vv; j += BLOCK) REF1(row[j]);
    }
    __syncthreads();
    if (wave == 0) {
        int b2w; float A2w;
        find_crit_desc(hist, 4096, 64, A, limit, lane, &b2w, &A2w);
        if (lane == 0) ub[0] = (((unsigned)b1 << 12) | (unsigned)b2w) << 7;
    }
    __syncthreads();
    const unsigned T = ub[0];   // kept <=> float bits of e >= T

    // ---------------- P4: 1024-elem chunk sums of kept mass ----------------
    const int nch = (Vv + 1023) >> 10;
#define KEEP1(ss) { float e = __expf((ss) * inv_t - M); \
                    if (__float_as_uint(e) >= T) s += e; }
    for (int c = wave; c < nch; c += NW) {
        float s = 0.f;
        int base = c << 10;
#pragma unroll
        for (int q = 0; q < 4; q++) {
            int i = base + q * 256 + lane * 4;
            if (i + 3 < Vv) {
                float4 v = LD4(i);
                KEEP1(v.x); KEEP1(v.y); KEEP1(v.z); KEEP1(v.w);
            } else {
                for (int k = 0; k < 4; k++)
                    if (i + k < Vv) KEEP1(row[i + k]);
            }
        }
#pragma unroll
        for (int o = 32; o >= 1; o >>= 1) s += __shfl_xor(s, o, 64);
        if (lane == 0) csum[c] = s;
    }
    if (t < 128 && t >= nch) csum[t] = 0.f;
    __syncthreads();

    // ---------------- final: locate token in the crossing chunk ----------------
    if (wave == 0) {
        float segsum = csum[lane * 2] + csum[lane * 2 + 1];
        float incl = wincl(segsum, lane);
        float total = __shfl(incl, 63, 64);            // Z_kept
        const float U = uvec[b] * total;
        unsigned long long mk = __ballot(incl >= U);
        int token;
        if (mk == 0ULL) {
            token = Vv;
        } else {
            int fl = __ffsll(mk) - 1;
            float base = __shfl(incl, fl, 64) - __shfl(segsum, fl, 64);
            float v = (lane < 2) ? csum[fl * 2 + lane] : 0.f;
            float incl2 = wincl(v, lane);
            unsigned long long mk2 = __ballot((lane < 2) && (base + incl2 >= U));
            int k2 = mk2 ? (__ffsll(mk2) - 1) : 1;
            int cx = fl * 2 + k2;                      // crossing chunk
            float B = base + __shfl(incl2, k2, 64) - __shfl(v, k2, 64);
            int cb = cx << 10;
            // preload the whole chunk (16 rounds of 64) into registers
            float vv[16];
#pragma unroll
            for (int r = 0; r < 16; r++) {
                int idx = cb + r * 64 + lane;
                vv[r] = (idx < Vv) ? row[idx] : -1e30f;
            }
            int cnt = 0;
#pragma unroll
            for (int r = 0; r < 16; r++) {
                int idx = cb + r * 64 + lane;
                float e = __expf(vv[r] * inv_t - M);
                float keep = (__float_as_uint(e) >= T) ? e : 0.f;
                float is = wincl(keep, lane);
                unsigned long long mm = __ballot((idx < Vv) && (B + is < U));
                cnt += __popcll(mm);
                B += __shfl(is, 63, 64);
            }
            token = cb + cnt;
        }
        if (lane == 0) out[b] = (token < Vv - 1) ? token : (Vv - 1);
    }
}

extern "C" void kernel_launch(void* const* d_in, const int* in_sizes, int n_in,
                              void* d_out, int out_size, void* d_ws, size_t ws_size,
                              hipStream_t stream) {
    const float* logits = (const float*)d_in[0];
    const float* u = (const float*)d_in[1];
    const int* temp = (const int*)d_in[2];
    int* out = (int*)d_out;
    int B = in_sizes[1];
    int V = in_sizes[0] / B;
    NucleusSampling_79336635892529_kernel<<<B, BLOCK, 0, stream>>>(logits, u, temp, out, V);
}

// Round 3
// 238.926 us; speedup vs baseline: 1.6393x; 1.6225x over previous
//
#include <hip/hip_runtime.h>
#include <cmath>

#define BLOCK 1024
#define NW (BLOCK / 64)
#define LISTCAP 4096

// inclusive scan across a 64-lane wave (lane order = index order)
__device__ __forceinline__ float wincl(float v, int lane) {
#pragma unroll
    for (int o = 1; o < 64; o <<= 1) {
        float x = __shfl_up(v, o, 64);
        if (lane >= o) v += x;
    }
    return v;
}

// Walk buckets in DESCENDING value order; find first bucket where running
// inclusive mass (starting at base0) exceeds limit. One full wave executes.
__device__ __forceinline__ void find_crit_desc(const float* h, int n, int seg,
                                               float base0, float limit, int lane,
                                               int* out_b, float* out_A) {
    float segsum = 0.f;
    int start = n - 1 - lane * seg;
    for (int k = 0; k < seg; k++) segsum += h[start - k];
    float incl = wincl(segsum, lane);
    unsigned long long mk = __ballot(base0 + incl > limit);
    if (mk == 0ULL) { *out_b = 0; *out_A = base0; return; }
    int fl = __ffsll(mk) - 1;
    float base = base0 + __shfl(incl, fl, 64) - __shfl(segsum, fl, 64);
    int sstart = n - 1 - fl * seg;
    float v = (lane < seg) ? h[sstart - lane] : 0.f;
    float incl2 = wincl(v, lane);
    unsigned long long mk2 = __ballot((lane < seg) && (base + incl2 > limit));
    int k2 = mk2 ? (__ffsll(mk2) - 1) : (seg - 1);
    *out_b = sstart - k2;
    *out_A = base + __shfl(incl2, k2, 64) - __shfl(v, k2, 64);
}

// monotone (total-order) key of a float's bit pattern
__device__ __forceinline__ unsigned okey(unsigned bits) {
    return (bits & 0x80000000u) ? ~bits : (bits | 0x80000000u);
}
// upper boundary (in value space) of L1 bucket b = keys [b<<21, (b+1)<<21)
__device__ __forceinline__ float bucket_hi(unsigned b) {
    unsigned ku = (b + 1u) << 21;
    unsigned hb = (ku & 0x80000000u) ? (ku & 0x7FFFFFFFu) : ~ku;
    return __uint_as_float(hb);
}

#define LD4(j) (*(const float4*)(row + (j)))

__global__ __launch_bounds__(BLOCK) void NucleusSampling_79336635892529_kernel(
    const float* __restrict__ logits, const float* __restrict__ uvec,
    const int* __restrict__ temp, int* __restrict__ out, int Vv) {
    const int b = blockIdx.x;
    const float* __restrict__ row = logits + (size_t)b * (size_t)Vv;
    const int t = threadIdx.x;
    const int lane = t & 63;
    const int wave = t >> 6;

    __shared__ float hist[4096];          // u32 fixed-point, then float masses
    __shared__ float sweep[NW];
    __shared__ float csum[128];           // 1024-elem chunk sums (V<=131072)
    __shared__ unsigned idxlist[LISTCAP]; // critical-bucket element indices
    __shared__ int shi[2];                // [0]=topIdx, [1]=b1
    __shared__ float shf[1];              // A
    __shared__ unsigned shu[1];           // T
    __shared__ int cnt;

    const float inv_t = 1.0f / (float)temp[0];
    const int V4 = Vv & ~3;
    const int S = BLOCK * 4;

    for (int i = t; i < 4096; i += BLOCK) hist[i] = 0.f;  // u32 zero == float 0
    if (t == 0) { shi[0] = 0; cnt = 0; }
    __syncthreads();

    // ---------------- Pass 1: L1 histogram (2048 buckets, fixed point 2^17) ---
    // mass accumulated relative to the bucket's own upper boundary: er in (0,1]
#define P1(xx) { unsigned bb = __float_as_uint(xx); unsigned kk = okey(bb); \
                 unsigned bk = kk >> 21; \
                 float er = __expf(((xx) - bucket_hi(bk)) * inv_t); \
                 atomicAdd((unsigned*)&hist[bk], (unsigned)(er * 131072.f + 0.5f)); }
    {
        int i = t * 4;
        for (; i + 3 * S + 3 < V4; i += 4 * S) {
            float4 a = LD4(i), b4 = LD4(i + S), c = LD4(i + 2 * S), d = LD4(i + 3 * S);
            P1(a.x); P1(a.y); P1(a.z); P1(a.w);
            P1(b4.x); P1(b4.y); P1(b4.z); P1(b4.w);
            P1(c.x); P1(c.y); P1(c.z); P1(c.w);
            P1(d.x); P1(d.y); P1(d.z); P1(d.w);
        }
        for (; i < V4; i += S) { float4 a = LD4(i); P1(a.x); P1(a.y); P1(a.z); P1(a.w); }
        for (int j = V4 + t; j < Vv; j += BLOCK) P1(row[j]);
    }
    __syncthreads();

    // top nonempty bucket -> global reference Ms (s-space)
    for (int i = t; i < 2048; i += BLOCK)
        if (__float_as_uint(hist[i])) atomicMax(&shi[0], i);
    __syncthreads();
    const float Ms = bucket_hi((unsigned)shi[0]) * inv_t;

    // convert u32 -> absolute float masses, and total Z
    float zp = 0.f;
    for (int i = t; i < 2048; i += BLOCK) {
        unsigned h = __float_as_uint(hist[i]);
        float mass = h ? (float)h * 0x1p-17f * __expf(bucket_hi((unsigned)i) * inv_t - Ms) : 0.f;
        hist[i] = mass;
        zp += mass;
    }
#pragma unroll
    for (int o = 32; o >= 1; o >>= 1) zp += __shfl_xor(zp, o, 64);
    if (lane == 0) sweep[wave] = zp;
    __syncthreads();
    float Z = 0.f;
    for (int w = 0; w < NW; w++) Z += sweep[w];
    const float limit = 0.9f * Z;

    // L1 walk
    if (wave == 0) {
        int b1w; float Aw;
        find_crit_desc(hist, 2048, 32, 0.f, limit, lane, &b1w, &Aw);
        if (lane == 0) { shi[1] = b1w; shf[0] = Aw; }
    }
    __syncthreads();
    const int b1 = shi[1];
    const float A = shf[0];
    const float xhi1s = bucket_hi((unsigned)b1) * inv_t;
    const float C1 = __expf(Ms - xhi1s);            // e_rel = e_abs * C1, < 1
    const unsigned Tlow = (unsigned)b1 << 21;

    for (int i = t; i < 4096; i += BLOCK) hist[i] = 0.f;   // refine hist
    __syncthreads();

    // ---------------- Pass 2: chunk sums (coarse keep) + compaction + refine ---
    const int nch = (Vv + 1023) >> 10;
#define P2(xx, ii) { unsigned bb = __float_as_uint(xx); unsigned kk = okey(bb); \
    if (kk >= Tlow) { \
        float e = __expf((xx) * inv_t - Ms); s += e; \
        if ((kk >> 21) == (unsigned)b1) { \
            int p = atomicAdd(&cnt, 1); \
            if (p < LISTCAP) idxlist[p] = (unsigned)(ii); \
            atomicAdd((unsigned*)&hist[(kk >> 9) & 0xFFF], \
                      (unsigned)(e * C1 * 131072.f + 0.5f)); \
        } } }
    for (int c = wave; c < nch; c += NW) {
        float s = 0.f;
        int base = c << 10;
#pragma unroll
        for (int q = 0; q < 4; q++) {
            int i = base + q * 256 + lane * 4;
            if (i + 3 < Vv) {
                float4 v = LD4(i);
                P2(v.x, i); P2(v.y, i + 1); P2(v.z, i + 2); P2(v.w, i + 3);
            } else {
                for (int kq = 0; kq < 4; kq++)
                    if (i + kq < Vv) P2(row[i + kq], i + kq);
            }
        }
#pragma unroll
        for (int o = 32; o >= 1; o >>= 1) s += __shfl_xor(s, o, 64);
        if (lane == 0) csum[c] = s;
    }
    if (t < 128 && t >= nch) csum[t] = 0.f;
    __syncthreads();

    // refine walk -> exact 23-bit threshold T: keep <=> okey >= T
    if (wave == 0) {
        int b2w; float A2;
        find_crit_desc(hist, 4096, 64, A, limit, lane, &b2w, &A2);
        if (lane == 0) shu[0] = (((unsigned)b1 << 12) | (unsigned)b2w) << 9;
    }
    __syncthreads();
    const unsigned T = shu[0];

    // corrections: remove crit-bucket elements below T from their chunk sums
    {
        int nc = cnt < LISTCAP ? cnt : LISTCAP;
        for (int p = t; p < nc; p += BLOCK) {
            unsigned ii = idxlist[p];
            float x = row[ii];
            unsigned kk = okey(__float_as_uint(x));
            if (kk < T) {
                float e = __expf(x * inv_t - Ms);
                atomicAdd(&csum[ii >> 10], -e);
            }
        }
    }
    __syncthreads();

    // ---------------- final: locate token in the crossing chunk ----------------
    if (wave == 0) {
        float segsum = csum[lane * 2] + csum[lane * 2 + 1];
        float incl = wincl(segsum, lane);
        float total = __shfl(incl, 63, 64);            // Z_kept
        const float U = uvec[b] * total;
        unsigned long long mk = __ballot(incl >= U);
        int token;
        if (mk == 0ULL) {
            token = Vv;
        } else {
            int fl = __ffsll(mk) - 1;
            float base = __shfl(incl, fl, 64) - __shfl(segsum, fl, 64);
            float v = (lane < 2) ? csum[fl * 2 + lane] : 0.f;
            float incl2 = wincl(v, lane);
            unsigned long long mk2 = __ballot((lane < 2) && (base + incl2 >= U));
            int k2 = mk2 ? (__ffsll(mk2) - 1) : 1;
            int cx = fl * 2 + k2;                      // crossing chunk
            float B = base + __shfl(incl2, k2, 64) - __shfl(v, k2, 64);
            int cb = cx << 10;
            float vv[16];
#pragma unroll
            for (int r = 0; r < 16; r++) {
                int idx = cb + r * 64 + lane;
                vv[r] = (idx < Vv) ? row[idx] : -1e30f;
            }
            int cnt2 = 0;
#pragma unroll
            for (int r = 0; r < 16; r++) {
                int idx = cb + r * 64 + lane;
                unsigned kk = okey(__float_as_uint(vv[r]));
                float e = __expf(vv[r] * inv_t - Ms);
                float keep = (kk >= T) ? e : 0.f;
                float is = wincl(keep, lane);
                unsigned long long mm = __ballot((idx < Vv) && (B + is < U));
                cnt2 += __popcll(mm);
                B += __shfl(is, 63, 64);
            }
            token = cb + cnt2;
        }
        if (lane == 0) out[b] = (token < Vv - 1) ? token : (Vv - 1);
    }
}

extern "C" void kernel_launch(void* const* d_in, const int* in_sizes, int n_in,
                              void* d_out, int out_size, void* d_ws, size_t ws_size,
                              hipStream_t stream) {
    const float* logits = (const float*)d_in[0];
    const float* u = (const float*)d_in[1];
    const int* temp = (const int*)d_in[2];
    int* out = (int*)d_out;
    int B = in_sizes[1];
    int V = in_sizes[0] / B;
    NucleusSampling_79336635892529_kernel<<<B, BLOCK, 0, stream>>>(logits, u, temp, out, V);
}